// Round 3
// baseline (33.070 us; speedup 1.0000x reference)
//
#include <hip/hip_runtime.h>
#include <math.h>

#define DT    0.019999999552965164f
#define GRAV  9.8100004196167f
#define GEAR  100.0f

// Per-element RK4 step. Physical params passed pre-combined.
__device__ __forceinline__ void rk4_one(
    float x0, float v0, float t0, float o0, float F,
    float b, float d, float M, float m2l, float Ieff, float m2gl, float IeffM,
    float4& outv)
{
    auto deriv = [&](float v_, float t_, float o_, float& xdd, float& tdd) {
        float s, c;
        __sincosf(t_, &s, &c);
        float A    = F - b * v_ + m2l * o_ * o_ * s;
        float Bq   = m2gl * s - d * o_;
        float mlc  = m2l * c;
        float D    = IeffM - mlc * mlc;
        float invD = __builtin_amdgcn_rcpf(D);
        xdd = (Ieff * A - mlc * Bq) * invD;
        tdd = (M * Bq - mlc * A) * invD;
    };

    const float half = 0.5f * DT;

    float k1v, k1o;
    deriv(v0, t0, o0, k1v, k1o);

    float v2 = v0 + half * k1v;
    float t2 = t0 + half * o0;
    float o2 = o0 + half * k1o;
    float k2v, k2o;
    deriv(v2, t2, o2, k2v, k2o);

    float v3 = v0 + half * k2v;
    float t3 = t0 + half * o2;
    float o3 = o0 + half * k2o;
    float k3v, k3o;
    deriv(v3, t3, o3, k3v, k3o);

    float v4 = v0 + DT * k3v;
    float t4 = t0 + DT * o3;
    float o4 = o0 + DT * k3o;
    float k4v, k4o;
    deriv(v4, t4, o4, k4v, k4o);

    const float w = DT * (1.0f / 6.0f);
    outv.x = x0 + w * (v0  + 2.0f * v2  + 2.0f * v3  + v4);
    outv.y = v0 + w * (k1v + 2.0f * k2v + 2.0f * k3v + k4v);
    outv.z = t0 + w * (o0  + 2.0f * o2  + 2.0f * o3  + o4);
    outv.w = o0 + w * (k1o + 2.0f * k2o + 2.0f * k3o + k4o);
}

__global__ __launch_bounds__(256) void cartpole_rk4_kernel(
    const float* __restrict__ x,
    const float* __restrict__ v,
    const float* __restrict__ th,
    const float* __restrict__ om,
    const float* __restrict__ u,
    const float* __restrict__ pI,
    const float* __restrict__ pb,
    const float* __restrict__ pd,
    const float* __restrict__ pl,
    const float* __restrict__ pm1,
    const float* __restrict__ pm2,
    float4* __restrict__ out,
    int n)
{
    const float I  = pI[0];
    const float b  = pb[0];
    const float d  = pd[0];
    const float l  = pl[0];
    const float m1 = pm1[0];
    const float m2 = pm2[0];

    const float M     = m1 + m2;
    const float m2l   = m2 * l;
    const float Ieff  = I + m2l * l;
    const float m2gl  = m2l * GRAV;
    const float IeffM = Ieff * M;

    int t = blockIdx.x * blockDim.x + threadIdx.x;
    int i0 = t * 4;

    if (i0 + 3 < n) {
        // vector path: float4 loads (16B/lane), 4 float4 stores (64B contiguous)
        float4 xv = *reinterpret_cast<const float4*>(x  + i0);
        float4 vv = *reinterpret_cast<const float4*>(v  + i0);
        float4 tv = *reinterpret_cast<const float4*>(th + i0);
        float4 ov = *reinterpret_cast<const float4*>(om + i0);
        float4 uv = *reinterpret_cast<const float4*>(u  + i0);

        float4 o0, o1, o2, o3;
        rk4_one(xv.x, vv.x, tv.x, ov.x, GEAR * uv.x, b, d, M, m2l, Ieff, m2gl, IeffM, o0);
        rk4_one(xv.y, vv.y, tv.y, ov.y, GEAR * uv.y, b, d, M, m2l, Ieff, m2gl, IeffM, o1);
        rk4_one(xv.z, vv.z, tv.z, ov.z, GEAR * uv.z, b, d, M, m2l, Ieff, m2gl, IeffM, o2);
        rk4_one(xv.w, vv.w, tv.w, ov.w, GEAR * uv.w, b, d, M, m2l, Ieff, m2gl, IeffM, o3);

        out[i0 + 0] = o0;
        out[i0 + 1] = o1;
        out[i0 + 2] = o2;
        out[i0 + 3] = o3;
    } else {
        // scalar tail (n not a multiple of 4)
        for (int i = i0; i < n; ++i) {
            float4 r;
            rk4_one(x[i], v[i], th[i], om[i], GEAR * u[i],
                    b, d, M, m2l, Ieff, m2gl, IeffM, r);
            out[i] = r;
        }
    }
}

extern "C" void kernel_launch(void* const* d_in, const int* in_sizes, int n_in,
                              void* d_out, int out_size, void* d_ws, size_t ws_size,
                              hipStream_t stream) {
    const float* x   = (const float*)d_in[0];
    const float* v   = (const float*)d_in[1];
    const float* th  = (const float*)d_in[2];
    const float* om  = (const float*)d_in[3];
    const float* u   = (const float*)d_in[4];
    const float* pI  = (const float*)d_in[5];
    const float* pb  = (const float*)d_in[6];
    const float* pd  = (const float*)d_in[7];
    const float* pl  = (const float*)d_in[8];
    const float* pm1 = (const float*)d_in[9];
    const float* pm2 = (const float*)d_in[10];

    int n = in_sizes[0];  // B = 4194304
    float4* out = (float4*)d_out;

    int block = 256;
    int elems_per_block = block * 4;
    int grid = (n + elems_per_block - 1) / elems_per_block;
    cartpole_rk4_kernel<<<grid, block, 0, stream>>>(
        x, v, th, om, u, pI, pb, pd, pl, pm1, pm2, out, n);
}

// Round 5
// 28.323 us; speedup vs baseline: 1.1676x; 1.1676x over previous
//
#include <hip/hip_runtime.h>
#include <math.h>

#define DT    0.019999999552965164f
#define GRAV  9.8100004196167f
#define GEAR  100.0f

// native clang vector type: __builtin_nontemporal_store accepts this
// (it rejects HIP's struct-wrapped float4).
typedef float vfloat4 __attribute__((ext_vector_type(4)));

__global__ __launch_bounds__(256) void cartpole_rk4_kernel(
    const float* __restrict__ x,
    const float* __restrict__ v,
    const float* __restrict__ th,
    const float* __restrict__ om,
    const float* __restrict__ u,
    const float* __restrict__ pI,
    const float* __restrict__ pb,
    const float* __restrict__ pd,
    const float* __restrict__ pl,
    const float* __restrict__ pm1,
    const float* __restrict__ pm2,
    vfloat4* __restrict__ out,
    int n)
{
    int i = blockIdx.x * blockDim.x + threadIdx.x;
    if (i >= n) return;

    // uniform physical parameters
    const float I  = pI[0];
    const float b  = pb[0];
    const float d  = pd[0];
    const float l  = pl[0];
    const float m1 = pm1[0];
    const float m2 = pm2[0];

    const float M     = m1 + m2;
    const float m2l   = m2 * l;
    const float Ieff  = I + m2l * l;        // I + m2*l*l
    const float m2gl  = m2l * GRAV;         // m2*g*l
    const float IeffM = Ieff * M;

    const float x0 = x[i];
    const float v0 = v[i];
    const float t0 = th[i];
    const float o0 = om[i];
    const float F  = GEAR * u[i];

    auto deriv = [&](float v_, float t_, float o_, float& xdd, float& tdd) {
        float s, c;
        __sincosf(t_, &s, &c);
        float A    = F - b * v_ + m2l * o_ * o_ * s;
        float Bq   = m2gl * s - d * o_;
        float mlc  = m2l * c;
        float D    = IeffM - mlc * mlc;
        float invD = __builtin_amdgcn_rcpf(D);
        xdd = (Ieff * A - mlc * Bq) * invD;
        tdd = (M * Bq - mlc * A) * invD;
    };

    const float half = 0.5f * DT;

    // k1
    float k1v, k1o;
    deriv(v0, t0, o0, k1v, k1o);

    // k2
    float v2 = v0 + half * k1v;
    float t2 = t0 + half * o0;
    float o2 = o0 + half * k1o;
    float k2v, k2o;
    deriv(v2, t2, o2, k2v, k2o);

    // k3
    float v3 = v0 + half * k2v;
    float t3 = t0 + half * o2;
    float o3 = o0 + half * k2o;
    float k3v, k3o;
    deriv(v3, t3, o3, k3v, k3o);

    // k4
    float v4 = v0 + DT * k3v;
    float t4 = t0 + DT * o3;
    float o4 = o0 + DT * k3o;
    float k4v, k4o;
    deriv(v4, t4, o4, k4v, k4o);

    const float w = DT * (1.0f / 6.0f);

    vfloat4 r;
    r.x = x0 + w * (v0  + 2.0f * v2  + 2.0f * v3  + v4);
    r.y = v0 + w * (k1v + 2.0f * k2v + 2.0f * k3v + k4v);
    r.z = t0 + w * (o0  + 2.0f * o2  + 2.0f * o3  + o4);
    r.w = o0 + w * (k1o + 2.0f * k2o + 2.0f * k3o + k4o);

    // streamed output, never re-read: nontemporal store keeps it out of the
    // cache-allocate path. Lane-contiguous 16B/lane = perfect coalescing.
    __builtin_nontemporal_store(r, out + i);
}

extern "C" void kernel_launch(void* const* d_in, const int* in_sizes, int n_in,
                              void* d_out, int out_size, void* d_ws, size_t ws_size,
                              hipStream_t stream) {
    const float* x   = (const float*)d_in[0];
    const float* v   = (const float*)d_in[1];
    const float* th  = (const float*)d_in[2];
    const float* om  = (const float*)d_in[3];
    const float* u   = (const float*)d_in[4];
    const float* pI  = (const float*)d_in[5];
    const float* pb  = (const float*)d_in[6];
    const float* pd  = (const float*)d_in[7];
    const float* pl  = (const float*)d_in[8];
    const float* pm1 = (const float*)d_in[9];
    const float* pm2 = (const float*)d_in[10];

    int n = in_sizes[0];  // B = 4194304
    vfloat4* out = (vfloat4*)d_out;

    int block = 256;
    int grid = (n + block - 1) / block;
    cartpole_rk4_kernel<<<grid, block, 0, stream>>>(
        x, v, th, om, u, pI, pb, pd, pl, pm1, pm2, out, n);
}